// Round 1
// baseline (161.539 us; speedup 1.0000x reference)
//
#include <hip/hip_runtime.h>

// UDTCWT direct: B=4, C=8, T=65536, J=8 levels.
// Level 1: x (B,8,T) -> phi (B,16,T), psi (B,16,T) [psi halves swapped]
// Levels j=1..7: phi (B,16,T) -> phi' (B,16,T), psi_j (B,16,T), dilation 2^j
// Output: yl = phi_final[:, :8, :]  then yh = [8][B][16][T]

static constexpr int B  = 4;
static constexpr int C  = 8;
static constexpr int C2 = 16;
static constexpr int T  = 65536;

// Ping-pong phi buffers as device globals (no ws_size assumption).
// Fully rewritten before every read each call -> deterministic.
__device__ float g_phi[2][B * C2 * T];

__global__ __launch_bounds__(256) void udtcwt_lvl1(
    const float* __restrict__ x,
    const float* __restrict__ h0o,
    const float* __restrict__ h1o,
    float* __restrict__ psi)            // -> yh[0] : [B][16][T]
{
    int idx = blockIdx.x * 256 + threadIdx.x;   // over B*C*T = 2^21
    int t  = idx & (T - 1);
    int bc = idx >> 16;                          // b*8 + c
    const float* xin = x + (size_t)bc * T;

    float f0[5], f1[7];
#pragma unroll
    for (int k = 0; k < 5; ++k) f0[k] = h0o[k];
#pragma unroll
    for (int k = 0; k < 7; ++k) f1[k] = h1o[k];

    // window x_zp[t-3 .. t+4] covers conv7 (offset -3..+3) and its shift,
    // conv5 (offset -2..+2) and its shift.
    float w[8];
#pragma unroll
    for (int k = 0; k < 8; ++k) {
        int i = t + k - 3;
        w[k] = (i >= 0 && i < T) ? xin[i] : 0.f;
    }

    float p_dir = 0.f, p_sh = 0.f, q_dir = 0.f, q_sh = 0.f;
#pragma unroll
    for (int k = 0; k < 5; ++k) { p_dir += w[k + 1] * f0[k]; p_sh += w[k + 2] * f0[k]; }
#pragma unroll
    for (int k = 0; k < 7; ++k) { q_dir += w[k]     * f1[k]; q_sh += w[k + 1] * f1[k]; }

    int b = bc >> 3, c = bc & 7;
    size_t base = (size_t)(b * C2 + c) * T + t;
    float* phi = g_phi[0];
    phi[base]                 = p_dir;   // direct -> channels 0..7
    phi[base + (size_t)8 * T] = p_sh;    // rolled (shift +1) -> channels 8..15
    // psi halves swapped: channels 0..7 = rolled, 8..15 = direct
    psi[base]                 = q_sh;
    psi[base + (size_t)8 * T] = q_dir;
}

__global__ __launch_bounds__(256) void udtcwt_lvlj(
    const float* __restrict__ h0a,
    const float* __restrict__ h1a,
    const float* __restrict__ h0b,
    const float* __restrict__ h1b,
    float* __restrict__ psi_out,        // -> yh[j] : [B][16][T]
    float* __restrict__ yl,             // used only when last
    int src, int dil, int last)
{
    int idx = blockIdx.x * 256 + threadIdx.x;   // over B*16*T = 2^22
    int t = idx & (T - 1);
    int c = (idx >> 16) & 15;
    int b = idx >> 20;

    const float* f0 = (c & 1) ? h0b : h0a;
    const float* f1 = (c & 1) ? h1b : h1a;
    float r0[10], r1[10];
#pragma unroll
    for (int k = 0; k < 10; ++k) { r0[k] = f0[k]; r1[k] = f1[k]; }

    const float* xin = g_phi[src] + (size_t)(b * C2 + c) * T;
    int p2 = (9 * dil) >> 1;            // 4.5*dil (dil even for j>=1)

    float s0 = 0.f, s1 = 0.f;
#pragma unroll
    for (int k = 0; k < 10; ++k) {
        int i = t + k * dil - p2;
        float v = (i >= 0 && i < T) ? xin[i] : 0.f;
        s0 += v * r0[k];
        s1 += v * r1[k];
    }

    psi_out[idx] = s1;
    if (!last) {
        g_phi[src ^ 1][idx] = s0;
    } else if (c < 8) {
        yl[(size_t)(b * 8 + c) * T + t] = s0;   // yl : [B][8][T]
    }
}

extern "C" void kernel_launch(void* const* d_in, const int* in_sizes, int n_in,
                              void* d_out, int out_size, void* d_ws, size_t ws_size,
                              hipStream_t stream)
{
    const float* x   = (const float*)d_in[0];
    const float* h0o = (const float*)d_in[1];
    const float* h1o = (const float*)d_in[2];
    const float* h0a = (const float*)d_in[3];
    const float* h1a = (const float*)d_in[4];
    const float* h0b = (const float*)d_in[5];
    const float* h1b = (const float*)d_in[6];

    float* out = (float*)d_out;
    float* yl  = out;                                  // [B][8][T]
    float* yh  = out + (size_t)B * C * T;              // [8][B][16][T]

    const int n1 = B * C * T;        // 2,097,152
    const int nj = B * C2 * T;       // 4,194,304

    udtcwt_lvl1<<<n1 / 256, 256, 0, stream>>>(x, h0o, h1o, yh);

    for (int j = 1; j < 8; ++j) {
        int src  = (j - 1) & 1;      // lvl1 wrote buffer 0
        int last = (j == 7);
        udtcwt_lvlj<<<nj / 256, 256, 0, stream>>>(
            h0a, h1a, h0b, h1b,
            yh + (size_t)j * nj, yl,
            src, 1 << j, last);
    }
}

// Round 4
// 69.442 us; speedup vs baseline: 2.3262x; 2.3262x over previous
//
#include <hip/hip_runtime.h>

// Fused UDTCWT: all 8 levels in one kernel, phi chain kept in LDS.
// B=4, C=8 input channels -> 16 chains (direct/shifted), T=65536.
// Output: yl [4][8][T] then yh [8][4][16][T].

static constexpr int B   = 4;
static constexpr int C2  = 16;
static constexpr int T   = 65536;
static constexpr int TS  = 2048;          // outputs per tile
static constexpr int HB  = 1152;          // staged halo each side
static constexpr int S   = TS + 2 * HB;   // 4352 floats per LDS buffer
static constexpr int NT  = 256;

// Margins (validity half-width beyond [t0, t0+TS)) after each level.
// Level-1 produces margin 1148; dilated level D consumes 9*D/2.
// 1148 -> 1136 -> 1116 -> 1080 -> 1008 -> 864 -> 576 -> 0  (all %4==0)

template <int D, int MO, bool LAST>
__device__ __forceinline__ void lvl_pass(
    const float* __restrict__ in, float* __restrict__ out,
    const float (&f0)[10], const float (&f1)[10],
    float* __restrict__ psi_g, float* __restrict__ yl_g,
    int gbase, int tid, bool wr_yl)
{
    constexpr int HALF  = 9 * D / 2;
    constexpr int START = HB - MO;           // %4 == 0
    constexpr int END   = HB + TS + MO;
    for (int p4 = START + tid * 4; p4 < END; p4 += NT * 4) {
        float a[4]  = {0.f, 0.f, 0.f, 0.f};
        float bb[4] = {0.f, 0.f, 0.f, 0.f};
#pragma unroll
        for (int k = 0; k < 10; ++k) {
            const float* q = in + (p4 + k * D - HALF);
#pragma unroll
            for (int i = 0; i < 4; ++i) {
                float v = q[i];
                a[i]  += v * f0[k];
                bb[i] += v * f1[k];
            }
        }
        // psi -> global (only the tile's own [t0, t0+TS) range)
#pragma unroll
        for (int i = 0; i < 4; ++i) {
            if ((unsigned)(p4 + i - HB) < (unsigned)TS)
                psi_g[gbase + p4 + i] = bb[i];
        }
        if (!LAST) {
            // phi -> other LDS buffer, zero outside the signal [0,T)
#pragma unroll
            for (int i = 0; i < 4; ++i) {
                int g = gbase + p4 + i;
                out[p4 + i] = ((unsigned)g < (unsigned)T) ? a[i] : 0.f;
            }
        } else if (wr_yl) {
#pragma unroll
            for (int i = 0; i < 4; ++i) {
                if ((unsigned)(p4 + i - HB) < (unsigned)TS)
                    yl_g[gbase + p4 + i] = a[i];
            }
        }
    }
}

// Level 1: 5-tap phi, 7-tap psi.
// chain c2<8  (SH=0): phi = x[t+k-2], psi = x[t+k-2]  (psi halves pre-swapped)
// chain c2>=8 (SH=1): phi = x[t+k-1], psi = x[t+k-3]
template <int SH>
__device__ __forceinline__ void lvl1_pass(
    const float* __restrict__ in, float* __restrict__ out,
    const float* __restrict__ h0o, const float* __restrict__ h1o,
    float* __restrict__ psi_g, int gbase, int tid)
{
    float f0[5], f1[7];
#pragma unroll
    for (int k = 0; k < 5; ++k) f0[k] = h0o[k];
#pragma unroll
    for (int k = 0; k < 7; ++k) f1[k] = h1o[k];

    constexpr int WO    = SH ? -3 : -2;      // window origin vs output pos
    constexpr int FS    = SH ? 2 : 0;        // phi tap shift inside window
    constexpr int MO    = 1148;
    constexpr int START = HB - MO;           // 4
    constexpr int END   = HB + TS + MO;
    for (int p4 = START + tid * 4; p4 < END; p4 += NT * 4) {
        float w[10];
#pragma unroll
        for (int k = 0; k < 10; ++k) w[k] = in[p4 + WO + k];
        float a[4]  = {0.f, 0.f, 0.f, 0.f};
        float bb[4] = {0.f, 0.f, 0.f, 0.f};
#pragma unroll
        for (int i = 0; i < 4; ++i) {
#pragma unroll
            for (int k = 0; k < 5; ++k) a[i] += w[i + k + FS] * f0[k];
#pragma unroll
            for (int k = 0; k < 7; ++k) bb[i] += w[i + k] * f1[k];
        }
#pragma unroll
        for (int i = 0; i < 4; ++i) {
            if ((unsigned)(p4 + i - HB) < (unsigned)TS)
                psi_g[gbase + p4 + i] = bb[i];
        }
#pragma unroll
        for (int i = 0; i < 4; ++i) {
            int g = gbase + p4 + i;
            out[p4 + i] = ((unsigned)g < (unsigned)T) ? a[i] : 0.f;
        }
    }
}

__global__ __launch_bounds__(256, 4) void udtcwt_fused(
    const float* __restrict__ x,
    const float* __restrict__ h0o, const float* __restrict__ h1o,
    const float* __restrict__ h0a, const float* __restrict__ h1a,
    const float* __restrict__ h0b, const float* __restrict__ h1b,
    float* __restrict__ out)
{
    __shared__ float bufA[S];
    __shared__ float bufB[S];

    const int tid   = threadIdx.x;
    const int bid   = blockIdx.x;
    const int tile  = bid & 31;          // 32 tiles of TS
    const int chain = bid >> 5;          // 0..63
    const int shbit = chain & 1;         // direct/shifted phi chain
    const int cx    = (chain >> 1) & 7;  // input channel
    const int b     = chain >> 4;
    const int c2    = shbit * 8 + cx;    // chain channel 0..15
    const int t0    = tile * TS;
    const int gbase = t0 - HB;           // global index of LDS local 0

    // stage x tile + halo (zeros outside [0,T))
    const float* xin = x + (size_t)(b * 8 + cx) * T;
    for (int p = tid; p < S; p += NT) {
        int g = gbase + p;
        bufA[p] = ((unsigned)g < (unsigned)T) ? xin[g] : 0.f;
    }

    // per-chain filters for dilated levels (a for even channel, b for odd)
    float f0[10], f1[10];
    {
        const float* F0 = (c2 & 1) ? h0b : h0a;
        const float* F1 = (c2 & 1) ? h1b : h1a;
#pragma unroll
        for (int k = 0; k < 10; ++k) { f0[k] = F0[k]; f1[k] = F1[k]; }
    }

    float* yl_g = out + (size_t)(b * 8 + c2) * T;           // c2<8 only
    float* yh   = out + (size_t)B * 8 * T;                  // 2,097,152
    const size_t LS = (size_t)B * C2 * T;                   // 4,194,304
    float* psi0 = yh + (size_t)(b * C2 + c2) * T;

    __syncthreads();
    if (shbit) lvl1_pass<1>(bufA, bufB, h0o, h1o, psi0, gbase, tid);
    else       lvl1_pass<0>(bufA, bufB, h0o, h1o, psi0, gbase, tid);
    __syncthreads();
    lvl_pass<  2, 1136, false>(bufB, bufA, f0, f1, psi0 + 1 * LS, nullptr, gbase, tid, false);
    __syncthreads();
    lvl_pass<  4, 1116, false>(bufA, bufB, f0, f1, psi0 + 2 * LS, nullptr, gbase, tid, false);
    __syncthreads();
    lvl_pass<  8, 1080, false>(bufB, bufA, f0, f1, psi0 + 3 * LS, nullptr, gbase, tid, false);
    __syncthreads();
    lvl_pass< 16, 1008, false>(bufA, bufB, f0, f1, psi0 + 4 * LS, nullptr, gbase, tid, false);
    __syncthreads();
    lvl_pass< 32,  864, false>(bufB, bufA, f0, f1, psi0 + 5 * LS, nullptr, gbase, tid, false);
    __syncthreads();
    lvl_pass< 64,  576, false>(bufA, bufB, f0, f1, psi0 + 6 * LS, nullptr, gbase, tid, false);
    __syncthreads();
    lvl_pass<128,    0, true >(bufB, bufA, f0, f1, psi0 + 7 * LS, yl_g, gbase, tid, c2 < 8);
}

extern "C" void kernel_launch(void* const* d_in, const int* in_sizes, int n_in,
                              void* d_out, int out_size, void* d_ws, size_t ws_size,
                              hipStream_t stream)
{
    const float* x   = (const float*)d_in[0];
    const float* h0o = (const float*)d_in[1];
    const float* h1o = (const float*)d_in[2];
    const float* h0a = (const float*)d_in[3];
    const float* h1a = (const float*)d_in[4];
    const float* h0b = (const float*)d_in[5];
    const float* h1b = (const float*)d_in[6];

    const int nblocks = 64 * (T / TS);   // 64 chains x 32 tiles = 2048
    udtcwt_fused<<<nblocks, NT, 0, stream>>>(x, h0o, h1o, h0a, h1a, h0b, h1b,
                                             (float*)d_out);
}

// Round 5
// 57.216 us; speedup vs baseline: 2.8233x; 1.2137x over previous
//
#include <hip/hip_runtime.h>

// Fused UDTCWT, polyphase edition: all 8 levels in one kernel, phi in LDS.
// Dilated levels use stride-D "polyphase" threads (W=9 outputs/thread) so
// tap windows overlap in registers: 18 LDS loads per 9 outputs (vs 10/output).
// B=4, C=8 -> 16 chains, T=65536. Output: yl [4][8][T], yh [8][4][16][T].

static constexpr int B   = 4;
static constexpr int C2  = 16;
static constexpr int T   = 65536;
static constexpr int TS  = 4096;          // outputs per tile
static constexpr int HB  = 1152;          // staged halo each side
static constexpr int S   = TS + 2 * HB;   // 6400 floats per LDS buffer
static constexpr int NT  = 256;

// Margin chain (validity beyond [t0,t0+TS) after each level):
// L1 out 1148; then consume 4.5*D: 1136 1116 1080 1008 864 576 0.

template <int D, int MO, bool LAST>
__device__ __forceinline__ void lvl_poly(
    const float* __restrict__ in, float* __restrict__ out,
    const float (&f0)[10], const float (&f1)[10],
    float* __restrict__ psi_g, float* __restrict__ yl_g,
    int gbase, int tid, bool wr_yl)
{
    constexpr int W     = 9;
    constexpr int HALF  = 9 * D / 2;
    constexpr int START = HB - MO;
    constexpr int END   = HB + TS + MO;
    constexpr int N     = END - START;
    static_assert(N % D == 0, "range must be divisible by dilation");
    constexpr int NPD   = N / D;             // outputs per residue class
    static_assert(NPD >= W, "");
    constexpr int CPC   = (NPD + W - 1) / W; // chunks per class
    constexpr int G     = D * CPC;           // thread-groups
    constexpr int LOG2D = (D == 2 ? 1 : D == 4 ? 2 : D == 8 ? 3 :
                           D == 16 ? 4 : D == 32 ? 5 : D == 64 ? 6 : 7);

    for (int g = tid; g < G; g += NT) {
        int r = g & (D - 1);
        int q = g >> LOG2D;
        int mstart = q * W;
        if (mstart > NPD - W) mstart = NPD - W;   // clamp last chunk (dup ok)
        int p0 = START + r + mstart * D;

        const float* src = in + (p0 - HALF);
        float v[W + 9];
#pragma unroll
        for (int n = 0; n < W + 9; ++n) v[n] = src[n * D];

        float a[W], bb[W];
#pragma unroll
        for (int m = 0; m < W; ++m) { a[m] = 0.f; bb[m] = 0.f; }
#pragma unroll
        for (int k = 0; k < 10; ++k) {
#pragma unroll
            for (int m = 0; m < W; ++m) {
                float x = v[m + k];
                a[m]  += x * f0[k];
                bb[m] += x * f1[k];
            }
        }

#pragma unroll
        for (int m = 0; m < W; ++m) {
            int p  = p0 + m * D;
            int gg = gbase + p;
            if ((unsigned)(p - HB) < (unsigned)TS) psi_g[gg] = bb[m];
            if constexpr (!LAST) {
                out[p] = ((unsigned)gg < (unsigned)T) ? a[m] : 0.f;
            } else {
                if (wr_yl && (unsigned)(p - HB) < (unsigned)TS)
                    yl_g[gg] = a[m];
            }
        }
    }
}

// Level 1: 5-tap phi, 7-tap psi, D=1. Quad-per-thread, float4 stores.
// chain c2<8  (SH=0): phi = x[t+k-2], psi = x[t+k-2] (halves pre-swapped)
// chain c2>=8 (SH=1): phi = x[t+k-1], psi = x[t+k-3]
template <int SH>
__device__ __forceinline__ void lvl1_pass(
    const float* __restrict__ in, float* __restrict__ out,
    const float* __restrict__ h0o, const float* __restrict__ h1o,
    float* __restrict__ psi_g, int gbase, int tid)
{
    float f0[5], f1[7];
#pragma unroll
    for (int k = 0; k < 5; ++k) f0[k] = h0o[k];
#pragma unroll
    for (int k = 0; k < 7; ++k) f1[k] = h1o[k];

    constexpr int WO    = SH ? -3 : -2;   // window origin vs output pos
    constexpr int FS    = SH ? 2 : 0;     // phi tap shift inside window
    constexpr int MO    = 1148;
    constexpr int START = HB - MO;        // 4
    constexpr int END   = HB + TS + MO;   // 6396

    for (int p4 = START + tid * 4; p4 < END; p4 += NT * 4) {
        float w[10];
#pragma unroll
        for (int k = 0; k < 10; ++k) w[k] = in[p4 + WO + k];
        float a[4]  = {0.f, 0.f, 0.f, 0.f};
        float bb[4] = {0.f, 0.f, 0.f, 0.f};
#pragma unroll
        for (int i = 0; i < 4; ++i) {
#pragma unroll
            for (int k = 0; k < 5; ++k) a[i] += w[i + k + FS] * f0[k];
#pragma unroll
            for (int k = 0; k < 7; ++k) bb[i] += w[i + k] * f1[k];
        }
        if ((unsigned)(p4 - HB) < (unsigned)TS)
            *(float4*)&psi_g[gbase + p4] = make_float4(bb[0], bb[1], bb[2], bb[3]);
        int gg = gbase + p4;   // %4 == 0 -> quad never straddles 0 or T
        float4 ph = ((unsigned)gg < (unsigned)T)
                  ? make_float4(a[0], a[1], a[2], a[3])
                  : make_float4(0.f, 0.f, 0.f, 0.f);
        *(float4*)&out[p4] = ph;
    }
}

__global__ __launch_bounds__(256, 3) void udtcwt_fused(
    const float* __restrict__ x,
    const float* __restrict__ h0o, const float* __restrict__ h1o,
    const float* __restrict__ h0a, const float* __restrict__ h1a,
    const float* __restrict__ h0b, const float* __restrict__ h1b,
    float* __restrict__ out)
{
    __shared__ float bufA[S];
    __shared__ float bufB[S];

    const int tid   = threadIdx.x;
    const int bid   = blockIdx.x;
    const int tile  = bid & 15;          // 16 tiles of TS=4096
    const int chain = bid >> 4;          // 0..63
    const int shbit = chain & 1;
    const int cx    = (chain >> 1) & 7;
    const int b     = chain >> 4;
    const int c2    = shbit * 8 + cx;
    const int gbase = tile * TS - HB;    // %4 == 0

    // stage x tile + halo (zeros outside [0,T)); all-quad aligned
    const float* xin = x + (size_t)(b * 8 + cx) * T;
    for (int i4 = tid * 4; i4 < S; i4 += NT * 4) {
        int gg = gbase + i4;             // %4==0: quad fully in or fully out
        float4 val = ((unsigned)gg < (unsigned)T)
                   ? *(const float4*)&xin[gg]
                   : make_float4(0.f, 0.f, 0.f, 0.f);
        *(float4*)&bufA[i4] = val;
    }

    float f0[10], f1[10];
    {
        const float* F0 = (c2 & 1) ? h0b : h0a;
        const float* F1 = (c2 & 1) ? h1b : h1a;
#pragma unroll
        for (int k = 0; k < 10; ++k) { f0[k] = F0[k]; f1[k] = F1[k]; }
    }

    float* yl_g = out + (size_t)(b * 8 + c2) * T;           // used when c2<8
    float* yh   = out + (size_t)B * 8 * T;
    const size_t LS = (size_t)B * C2 * T;
    float* psi0 = yh + (size_t)(b * C2 + c2) * T;
    const bool wr_yl = (c2 < 8);

    __syncthreads();
    if (shbit) lvl1_pass<1>(bufA, bufB, h0o, h1o, psi0, gbase, tid);
    else       lvl1_pass<0>(bufA, bufB, h0o, h1o, psi0, gbase, tid);
    __syncthreads();
    lvl_poly<  2, 1136, false>(bufB, bufA, f0, f1, psi0 + 1 * LS, nullptr, gbase, tid, false);
    __syncthreads();
    lvl_poly<  4, 1116, false>(bufA, bufB, f0, f1, psi0 + 2 * LS, nullptr, gbase, tid, false);
    __syncthreads();
    lvl_poly<  8, 1080, false>(bufB, bufA, f0, f1, psi0 + 3 * LS, nullptr, gbase, tid, false);
    __syncthreads();
    lvl_poly< 16, 1008, false>(bufA, bufB, f0, f1, psi0 + 4 * LS, nullptr, gbase, tid, false);
    __syncthreads();
    lvl_poly< 32,  864, false>(bufB, bufA, f0, f1, psi0 + 5 * LS, nullptr, gbase, tid, false);
    __syncthreads();
    lvl_poly< 64,  576, false>(bufA, bufB, f0, f1, psi0 + 6 * LS, nullptr, gbase, tid, false);
    __syncthreads();
    lvl_poly<128,    0, true >(bufB, bufA, f0, f1, psi0 + 7 * LS, yl_g, gbase, tid, wr_yl);
}

extern "C" void kernel_launch(void* const* d_in, const int* in_sizes, int n_in,
                              void* d_out, int out_size, void* d_ws, size_t ws_size,
                              hipStream_t stream)
{
    const float* x   = (const float*)d_in[0];
    const float* h0o = (const float*)d_in[1];
    const float* h1o = (const float*)d_in[2];
    const float* h0a = (const float*)d_in[3];
    const float* h1a = (const float*)d_in[4];
    const float* h0b = (const float*)d_in[5];
    const float* h1b = (const float*)d_in[6];

    const int nblocks = 64 * (T / TS);   // 64 chains x 16 tiles = 1024
    udtcwt_fused<<<nblocks, NT, 0, stream>>>(x, h0o, h1o, h0a, h1a, h0b, h1b,
                                             (float*)d_out);
}